// Round 2
// baseline (2193.134 us; speedup 1.0000x reference)
//
#include <hip/hip_runtime.h>
#include <hip/hip_bf16.h>

// ---------------------------------------------------------------------------
// GCN 2-layer + edge dot logits.
// x:[N,128] f32, edge_index:[2,E] int32 (harness converts ints to int32!),
// W1:[128,128], b1:[128], W2:[128,64], b2:[64] -> logits[E] f32
// ---------------------------------------------------------------------------

__global__ void deg_init_k(float* __restrict__ deg, int N) {
    int i = blockIdx.x * blockDim.x + threadIdx.x;
    if (i < N) deg[i] = 1.0f;  // self-loop
}

__global__ void deg_count_k(const int* __restrict__ dst, float* __restrict__ deg, int E) {
    int e = blockIdx.x * blockDim.x + threadIdx.x;
    if (e < E) atomicAdd(&deg[dst[e]], 1.0f);
}

__global__ void deg_rsqrt_k(float* __restrict__ deg, int N) {
    int i = blockIdx.x * blockDim.x + threadIdx.x;
    if (i < N) deg[i] = rsqrtf(deg[i]);  // deg >= 1 always
}

// ---------------------------------------------------------------------------
// Tiled fp32 GEMM: Out[M,BN] = (RELU? max(A,0) : A)[M,128] @ W[128,BN]
// BM=64, BK=16. 256 threads = (tx 0..15, ty 0..15). TM=4, TN=BN/16.
// ---------------------------------------------------------------------------
template <int BN, bool RELU>
__global__ __launch_bounds__(256) void gemm_k128(const float* __restrict__ A,
                                                 const float* __restrict__ W,
                                                 float* __restrict__ Out, int M) {
    constexpr int K = 128, BM = 64, BK = 16;
    constexpr int TN = BN / 16;
    __shared__ float As[BM][BK + 1];  // +1 pad: breaks bank conflict on A reads
    __shared__ float Bs[BK][BN];

    const int tid = threadIdx.x;
    const int tx = tid & 15, ty = tid >> 4;
    const int row0 = blockIdx.x * BM;

    float acc[4][TN];
#pragma unroll
    for (int m = 0; m < 4; m++)
#pragma unroll
        for (int j = 0; j < TN; j++) acc[m][j] = 0.0f;

    const int ar = tid >> 2;        // 0..63: A row within tile
    const int ak = (tid & 3) * 4;   // 0,4,8,12: k-offset of this thread's float4

    for (int kt = 0; kt < K; kt += BK) {
        // --- stage A tile (64x16) ---
        float4 av = make_float4(0.f, 0.f, 0.f, 0.f);
        int grow = row0 + ar;
        if (grow < M)
            av = *reinterpret_cast<const float4*>(A + (size_t)grow * K + kt + ak);
        if (RELU) {
            av.x = fmaxf(av.x, 0.f); av.y = fmaxf(av.y, 0.f);
            av.z = fmaxf(av.z, 0.f); av.w = fmaxf(av.w, 0.f);
        }
        As[ar][ak + 0] = av.x; As[ar][ak + 1] = av.y;
        As[ar][ak + 2] = av.z; As[ar][ak + 3] = av.w;

        // --- stage B tile (16xBN) ---
        constexpr int NB4 = BK * BN / 4;  // float4 count: 512 (BN=128) / 256 (BN=64)
#pragma unroll
        for (int b = 0; b < NB4 / 256; b++) {
            int f = b * 256 + tid;
            int brow = (f * 4) / BN;
            int bcol = (f * 4) % BN;
            float4 bv = *reinterpret_cast<const float4*>(W + (size_t)(kt + brow) * BN + bcol);
            *reinterpret_cast<float4*>(&Bs[brow][bcol]) = bv;
        }
        __syncthreads();

#pragma unroll
        for (int k = 0; k < BK; k++) {
            float a[4], bb[TN];
#pragma unroll
            for (int m = 0; m < 4; m++) a[m] = As[ty * 4 + m][k];
#pragma unroll
            for (int j = 0; j < TN; j++) bb[j] = Bs[k][tx + 16 * j];
#pragma unroll
            for (int m = 0; m < 4; m++)
#pragma unroll
                for (int j = 0; j < TN; j++) acc[m][j] = fmaf(a[m], bb[j], acc[m][j]);
        }
        __syncthreads();
    }

#pragma unroll
    for (int m = 0; m < 4; m++) {
        int gr = row0 + ty * 4 + m;
        if (gr < M) {
#pragma unroll
            for (int j = 0; j < TN; j++)
                Out[(size_t)gr * BN + tx + 16 * j] = acc[m][j];
        }
    }
}

// agg[v][k] = h[v][k]*dinv[v]^2 + bias[k]   (self-loop message + bias)
template <int NOUT>
__global__ void agg_init_k(const float* __restrict__ h, const float* __restrict__ dinv,
                           const float* __restrict__ bias, float* __restrict__ agg, int N) {
    constexpr int C4 = NOUT / 4;
    int idx = blockIdx.x * blockDim.x + threadIdx.x;
    int v = idx / C4, q = idx % C4;
    if (v >= N) return;
    float s = dinv[v];
    s = s * s;
    float4 hv = *reinterpret_cast<const float4*>(h + (size_t)v * NOUT + q * 4);
    float4 bv = *reinterpret_cast<const float4*>(bias + q * 4);
    float4 o = make_float4(fmaf(hv.x, s, bv.x), fmaf(hv.y, s, bv.y),
                           fmaf(hv.z, s, bv.z), fmaf(hv.w, s, bv.w));
    *reinterpret_cast<float4*>(agg + (size_t)v * NOUT + q * 4) = o;
}

// per-edge push: agg[dst] += h[src] * dinv[src]*dinv[dst]; NOUT/4 lanes per edge
template <int NOUT>
__global__ void scatter_k(const int* __restrict__ src, const int* __restrict__ dst,
                          const float* __restrict__ h, const float* __restrict__ dinv,
                          float* __restrict__ agg, int E) {
    constexpr int L = NOUT / 4;
    int t = blockIdx.x * blockDim.x + threadIdx.x;
    int e = t / L, q = t % L;
    if (e >= E) return;
    int s = src[e], d = dst[e];
    float norm = dinv[s] * dinv[d];
    float4 hv = *reinterpret_cast<const float4*>(h + (size_t)s * NOUT + q * 4);
    float* ap = agg + (size_t)d * NOUT + q * 4;
    atomicAdd(ap + 0, hv.x * norm);
    atomicAdd(ap + 1, hv.y * norm);
    atomicAdd(ap + 2, hv.z * norm);
    atomicAdd(ap + 3, hv.w * norm);
}

// logits[e] = dot(h2[src[e]], h2[dst[e]]) over 64 dims; 16 lanes/edge
__global__ void logits_k(const int* __restrict__ src, const int* __restrict__ dst,
                         const float* __restrict__ h2, float* __restrict__ out, int E) {
    int t = blockIdx.x * blockDim.x + threadIdx.x;
    int e = t >> 4, q = t & 15;
    if (e >= E) return;
    int s = src[e], d = dst[e];
    float4 a = *reinterpret_cast<const float4*>(h2 + (size_t)s * 64 + q * 4);
    float4 b = *reinterpret_cast<const float4*>(h2 + (size_t)d * 64 + q * 4);
    float p = a.x * b.x + a.y * b.y + a.z * b.z + a.w * b.w;
#pragma unroll
    for (int off = 1; off < 16; off <<= 1) p += __shfl_xor(p, off);
    if (q == 0) out[e] = p;
}

extern "C" void kernel_launch(void* const* d_in, const int* in_sizes, int n_in,
                              void* d_out, int out_size, void* d_ws, size_t ws_size,
                              hipStream_t stream) {
    const float* x  = (const float*)d_in[0];
    const int* ei   = (const int*)d_in[1];   // int32! harness converts integer inputs
    const float* W1 = (const float*)d_in[2];
    const float* b1 = (const float*)d_in[3];
    const float* W2 = (const float*)d_in[4];
    const float* b2 = (const float*)d_in[5];
    float* out = (float*)d_out;

    const int N = in_sizes[0] / 128;     // 50000
    const int E = in_sizes[1] / 2;       // 800000
    const int* src = ei;
    const int* dst = ei + E;

    // workspace layout (floats), peak 51.4 MB with overlap:
    //   dinv[50176] | bufA[N*128] | bufB[N*128]
    //   h1   = bufA              (layer-1 GEMM out; dead after scatter1)
    //   agg1 = bufB              (layer-1 aggregated)
    //   g2   = bufA[0 .. N*64)   (layer-2 GEMM out, reuses dead h1 space)
    //   agg2 = bufA[N*64 .. N*128)
    float* ws   = (float*)d_ws;
    float* dinv = ws;
    float* bufA = ws + 50176;
    float* bufB = bufA + (size_t)N * 128;
    float* h1   = bufA;
    float* agg1 = bufB;
    float* g2   = bufA;
    float* agg2 = bufA + (size_t)N * 64;

    const int B = 256;
    // degree + dinv
    deg_init_k<<<(N + B - 1) / B, B, 0, stream>>>(dinv, N);
    deg_count_k<<<(E + B - 1) / B, B, 0, stream>>>(dst, dinv, E);
    deg_rsqrt_k<<<(N + B - 1) / B, B, 0, stream>>>(dinv, N);

    // layer 1: h1 = x @ W1; agg1 = self*dinv^2 + b1 + edge scatter
    gemm_k128<128, false><<<(N + 63) / 64, 256, 0, stream>>>(x, W1, h1, N);
    {
        long long t = (long long)N * 32;
        agg_init_k<128><<<(unsigned)((t + B - 1) / B), B, 0, stream>>>(h1, dinv, b1, agg1, N);
    }
    {
        long long t = (long long)E * 32;
        scatter_k<128><<<(unsigned)((t + B - 1) / B), B, 0, stream>>>(src, dst, h1, dinv, agg1, E);
    }

    // layer 2: g2 = relu(agg1) @ W2; agg2 = self*dinv^2 + b2 + edge scatter
    gemm_k128<64, true><<<(N + 63) / 64, 256, 0, stream>>>(agg1, W2, g2, N);
    {
        long long t = (long long)N * 16;
        agg_init_k<64><<<(unsigned)((t + B - 1) / B), B, 0, stream>>>(g2, dinv, b2, agg2, N);
    }
    {
        long long t = (long long)E * 16;
        scatter_k<64><<<(unsigned)((t + B - 1) / B), B, 0, stream>>>(src, dst, g2, dinv, agg2, E);
    }

    // edge logits from agg2
    {
        long long t = (long long)E * 16;
        logits_k<<<(unsigned)((t + B - 1) / B), B, 0, stream>>>(src, dst, agg2, out, E);
    }
}

// Round 3
// 327.632 us; speedup vs baseline: 6.6939x; 6.6939x over previous
//
#include <hip/hip_runtime.h>
#include <hip/hip_bf16.h>

// ---------------------------------------------------------------------------
// GCN 2-layer + edge dot logits, CSR-pull aggregation (no float atomics).
// x:[N,128] f32, edge_index:[2,E] int32, W1:[128,128], b1:[128],
// W2:[128,64], b2:[64] -> logits[E] f32
//
// agg[d] = dinv[d] * ( sum_{s in in(d)} h[s]*dinv[s]  +  h[d]*dinv[d] ) + b
// so GEMM epilogue writes h_scaled = (A@W)*dinv[row]; pull is a plain gather-sum.
// ---------------------------------------------------------------------------

__global__ void cnt_k(const int* __restrict__ dst, int* __restrict__ cnt, int E) {
    int e = blockIdx.x * blockDim.x + threadIdx.x;
    if (e < E) atomicAdd(&cnt[dst[e]], 1);
}

__global__ void dinv_k(const int* __restrict__ cnt, float* __restrict__ dinv, int N) {
    int i = blockIdx.x * blockDim.x + threadIdx.x;
    if (i < N) dinv[i] = rsqrtf(1.0f + (float)cnt[i]);  // +1 self-loop
}

// --- 3-kernel exclusive scan over cnt[N] (N=50000, 196 blocks of 256) ---
__global__ void scan1_k(const int* __restrict__ cnt, int* __restrict__ incl,
                        int* __restrict__ bsum, int N) {
    __shared__ int sh[256];
    int i = blockIdx.x * 256 + threadIdx.x;
    int v = (i < N) ? cnt[i] : 0;
    sh[threadIdx.x] = v;
    __syncthreads();
#pragma unroll
    for (int off = 1; off < 256; off <<= 1) {
        int t = (threadIdx.x >= off) ? sh[threadIdx.x - off] : 0;
        __syncthreads();
        sh[threadIdx.x] += t;
        __syncthreads();
    }
    if (i < N) incl[i] = sh[threadIdx.x];
    if (threadIdx.x == 255) bsum[blockIdx.x] = sh[255];
}

__global__ void scan2_k(int* __restrict__ bsum, int NB) {
    __shared__ int sh[256];
    int v = (threadIdx.x < NB) ? bsum[threadIdx.x] : 0;
    sh[threadIdx.x] = v;
    __syncthreads();
#pragma unroll
    for (int off = 1; off < 256; off <<= 1) {
        int t = (threadIdx.x >= off) ? sh[threadIdx.x - off] : 0;
        __syncthreads();
        sh[threadIdx.x] += t;
        __syncthreads();
    }
    if (threadIdx.x < NB) bsum[threadIdx.x] = sh[threadIdx.x] - v;  // exclusive
}

__global__ void scan3_k(const int* __restrict__ cnt, const int* __restrict__ incl,
                        const int* __restrict__ bsum, int* __restrict__ rowptr,
                        int* __restrict__ cursor, int N, int E) {
    int i = blockIdx.x * 256 + threadIdx.x;
    if (i < N) {
        int excl = incl[i] - cnt[i] + bsum[blockIdx.x];
        rowptr[i] = excl;
        cursor[i] = excl;
    }
    if (i == 0) rowptr[N] = E;
}

__global__ void fill_col_k(const int* __restrict__ src, const int* __restrict__ dst,
                           int* __restrict__ cursor, int* __restrict__ col, int E) {
    int e = blockIdx.x * blockDim.x + threadIdx.x;
    if (e < E) {
        int pos = atomicAdd(&cursor[dst[e]], 1);
        col[pos] = src[e];
    }
}

// ---------------------------------------------------------------------------
// Tiled fp32 GEMM: Out[M,BN] = (RELU? max(A,0):A)[M,128] @ W[128,BN], then
// row-scaled by dscale[row] (epilogue). BM=64, BK=16, 256 threads.
// ---------------------------------------------------------------------------
template <int BN, bool RELU>
__global__ __launch_bounds__(256) void gemm_k128(const float* __restrict__ A,
                                                 const float* __restrict__ W,
                                                 const float* __restrict__ dscale,
                                                 float* __restrict__ Out, int M) {
    constexpr int K = 128, BM = 64, BK = 16;
    constexpr int TN = BN / 16;
    __shared__ float As[BM][BK + 1];
    __shared__ float Bs[BK][BN];

    const int tid = threadIdx.x;
    const int tx = tid & 15, ty = tid >> 4;
    const int row0 = blockIdx.x * BM;

    float acc[4][TN];
#pragma unroll
    for (int m = 0; m < 4; m++)
#pragma unroll
        for (int j = 0; j < TN; j++) acc[m][j] = 0.0f;

    const int ar = tid >> 2;
    const int ak = (tid & 3) * 4;

    for (int kt = 0; kt < K; kt += BK) {
        float4 av = make_float4(0.f, 0.f, 0.f, 0.f);
        int grow = row0 + ar;
        if (grow < M)
            av = *reinterpret_cast<const float4*>(A + (size_t)grow * K + kt + ak);
        if (RELU) {
            av.x = fmaxf(av.x, 0.f); av.y = fmaxf(av.y, 0.f);
            av.z = fmaxf(av.z, 0.f); av.w = fmaxf(av.w, 0.f);
        }
        As[ar][ak + 0] = av.x; As[ar][ak + 1] = av.y;
        As[ar][ak + 2] = av.z; As[ar][ak + 3] = av.w;

        constexpr int NB4 = BK * BN / 4;
#pragma unroll
        for (int b = 0; b < NB4 / 256; b++) {
            int f = b * 256 + tid;
            int brow = (f * 4) / BN;
            int bcol = (f * 4) % BN;
            float4 bv = *reinterpret_cast<const float4*>(W + (size_t)(kt + brow) * BN + bcol);
            *reinterpret_cast<float4*>(&Bs[brow][bcol]) = bv;
        }
        __syncthreads();

#pragma unroll
        for (int k = 0; k < BK; k++) {
            float a[4], bb[TN];
#pragma unroll
            for (int m = 0; m < 4; m++) a[m] = As[ty * 4 + m][k];
#pragma unroll
            for (int j = 0; j < TN; j++) bb[j] = Bs[k][tx + 16 * j];
#pragma unroll
            for (int m = 0; m < 4; m++)
#pragma unroll
                for (int j = 0; j < TN; j++) acc[m][j] = fmaf(a[m], bb[j], acc[m][j]);
        }
        __syncthreads();
    }

#pragma unroll
    for (int m = 0; m < 4; m++) {
        int gr = row0 + ty * 4 + m;
        if (gr < M) {
            float dv = dscale[gr];
#pragma unroll
            for (int j = 0; j < TN; j++)
                Out[(size_t)gr * BN + tx + 16 * j] = acc[m][j] * dv;
        }
    }
}

// ---------------------------------------------------------------------------
// Pull aggregation: one wave per node.
// out[v] = dinv[v] * ( hs[v] + sum_{p in [rowptr[v],rowptr[v+1])} hs[col[p]] ) + bias
// D=128: float2/lane; D=64: float/lane.
// ---------------------------------------------------------------------------
template <int D>
__global__ __launch_bounds__(256) void pull_k(const int* __restrict__ rowptr,
                                              const int* __restrict__ col,
                                              const float* __restrict__ hs,
                                              const float* __restrict__ dinv,
                                              const float* __restrict__ bias,
                                              float* __restrict__ out, int N) {
    int v = (int)((blockIdx.x * (size_t)blockDim.x + threadIdx.x) >> 6);
    int lane = threadIdx.x & 63;
    if (v >= N) return;
    int p0 = rowptr[v], p1 = rowptr[v + 1];
    float dv = dinv[v];

    if (D == 128) {
        float2 acc = *reinterpret_cast<const float2*>(hs + (size_t)v * 128 + lane * 2);
        int p = p0;
        for (; p + 1 < p1; p += 2) {
            int s0 = col[p], s1 = col[p + 1];
            float2 a = *reinterpret_cast<const float2*>(hs + (size_t)s0 * 128 + lane * 2);
            float2 b = *reinterpret_cast<const float2*>(hs + (size_t)s1 * 128 + lane * 2);
            acc.x += a.x + b.x;
            acc.y += a.y + b.y;
        }
        if (p < p1) {
            int s0 = col[p];
            float2 a = *reinterpret_cast<const float2*>(hs + (size_t)s0 * 128 + lane * 2);
            acc.x += a.x;
            acc.y += a.y;
        }
        float2 bv = *reinterpret_cast<const float2*>(bias + lane * 2);
        float2 o = make_float2(fmaf(acc.x, dv, bv.x), fmaf(acc.y, dv, bv.y));
        *reinterpret_cast<float2*>(out + (size_t)v * 128 + lane * 2) = o;
    } else {
        float acc = hs[(size_t)v * 64 + lane];
        int p = p0;
        for (; p + 1 < p1; p += 2) {
            int s0 = col[p], s1 = col[p + 1];
            acc += hs[(size_t)s0 * 64 + lane] + hs[(size_t)s1 * 64 + lane];
        }
        if (p < p1) acc += hs[(size_t)col[p] * 64 + lane];
        out[(size_t)v * 64 + lane] = fmaf(acc, dv, bias[lane]);
    }
}

// logits[e] = dot(h2[src[e]], h2[dst[e]]) over 64 dims; 16 lanes/edge
__global__ void logits_k(const int* __restrict__ src, const int* __restrict__ dst,
                         const float* __restrict__ h2, float* __restrict__ out, int E) {
    int t = blockIdx.x * blockDim.x + threadIdx.x;
    int e = t >> 4, q = t & 15;
    if (e >= E) return;
    int s = src[e], d = dst[e];
    float4 a = *reinterpret_cast<const float4*>(h2 + (size_t)s * 64 + q * 4);
    float4 b = *reinterpret_cast<const float4*>(h2 + (size_t)d * 64 + q * 4);
    float p = a.x * b.x + a.y * b.y + a.z * b.z + a.w * b.w;
#pragma unroll
    for (int off = 1; off < 16; off <<= 1) p += __shfl_xor(p, off);
    if (q == 0) out[e] = p;
}

extern "C" void kernel_launch(void* const* d_in, const int* in_sizes, int n_in,
                              void* d_out, int out_size, void* d_ws, size_t ws_size,
                              hipStream_t stream) {
    const float* x  = (const float*)d_in[0];
    const int* ei   = (const int*)d_in[1];   // int32 (harness converts ints)
    const float* W1 = (const float*)d_in[2];
    const float* b1 = (const float*)d_in[3];
    const float* W2 = (const float*)d_in[4];
    const float* b2 = (const float*)d_in[5];
    float* out = (float*)d_out;

    const int N = in_sizes[0] / 128;   // 50000
    const int E = in_sizes[1] / 2;     // 800000
    const int* src = ei;
    const int* dst = ei + E;

    // ---- workspace layout ----
    // floats: dinv[50176] | bufA[N*128] | bufB[N*128]
    //   hs1 = bufA; agg1 = bufB; g2s = bufA[0,N*64); agg2 = bufA[N*64, N*128)
    // ints (after floats): cnt[N] | incl[N] | rowptr[N+1] | cursor[N] | bsum[256] | col[E]
    float* ws   = (float*)d_ws;
    float* dinv = ws;
    float* bufA = ws + 50176;
    float* bufB = bufA + (size_t)N * 128;
    float* hs1  = bufA;
    float* agg1 = bufB;
    float* g2s  = bufA;
    float* agg2 = bufA + (size_t)N * 64;

    int* ibase  = (int*)(bufB + (size_t)N * 128);
    int* cnt    = ibase;
    int* incl   = cnt + N;
    int* rowptr = incl + N;
    int* cursor = rowptr + (N + 1);
    int* bsum   = cursor + N;
    int* col    = bsum + 256;

    const int B = 256;
    const int NB = (N + 255) / 256;  // scan blocks (196)

    // ---- CSR build ----
    hipMemsetAsync(cnt, 0, (size_t)N * sizeof(int), stream);
    cnt_k<<<(E + B - 1) / B, B, 0, stream>>>(dst, cnt, E);
    dinv_k<<<NB, B, 0, stream>>>(cnt, dinv, N);
    scan1_k<<<NB, 256, 0, stream>>>(cnt, incl, bsum, N);
    scan2_k<<<1, 256, 0, stream>>>(bsum, NB);
    scan3_k<<<NB, 256, 0, stream>>>(cnt, incl, bsum, rowptr, cursor, N, E);
    fill_col_k<<<(E + B - 1) / B, B, 0, stream>>>(src, dst, cursor, col, E);

    // ---- layer 1: hs1 = (x@W1)*dinv ; agg1 = pull + b1 ----
    gemm_k128<128, false><<<(N + 63) / 64, 256, 0, stream>>>(x, W1, dinv, hs1, N);
    pull_k<128><<<(N * 64 + 255) / 256, 256, 0, stream>>>(rowptr, col, hs1, dinv, b1, agg1, N);

    // ---- layer 2: g2s = (relu(agg1)@W2)*dinv ; agg2 = pull + b2 ----
    gemm_k128<64, true><<<(N + 63) / 64, 256, 0, stream>>>(agg1, W2, dinv, g2s, N);
    pull_k<64><<<(N * 64 + 255) / 256, 256, 0, stream>>>(rowptr, col, g2s, dinv, b2, agg2, N);

    // ---- edge logits ----
    logits_k<<<((size_t)E * 16 + 255) / 256, 256, 0, stream>>>(src, dst, agg2, out, E);
}

// Round 4
// 285.348 us; speedup vs baseline: 7.6858x; 1.1482x over previous
//
#include <hip/hip_runtime.h>
#include <hip/hip_bf16.h>

// ---------------------------------------------------------------------------
// GCN 2-layer + edge dot logits, CSR-pull aggregation (no float atomics).
// agg[d] = dinv[d] * ( sum_{s in in(d)} hs[s] + hs[d] ) + b,  hs = (A@W)*dinv[row]
// ---------------------------------------------------------------------------

__global__ void cnt_k(const int* __restrict__ dst, int* __restrict__ cnt, int E) {
    int e = blockIdx.x * blockDim.x + threadIdx.x;
    if (e < E) atomicAdd(&cnt[dst[e]], 1);
}

// --- 3-kernel exclusive scan over cnt[N] ---
__global__ void scan1_k(const int* __restrict__ cnt, int* __restrict__ incl,
                        int* __restrict__ bsum, int N) {
    __shared__ int sh[256];
    int i = blockIdx.x * 256 + threadIdx.x;
    int v = (i < N) ? cnt[i] : 0;
    sh[threadIdx.x] = v;
    __syncthreads();
#pragma unroll
    for (int off = 1; off < 256; off <<= 1) {
        int t = (threadIdx.x >= off) ? sh[threadIdx.x - off] : 0;
        __syncthreads();
        sh[threadIdx.x] += t;
        __syncthreads();
    }
    if (i < N) incl[i] = sh[threadIdx.x];
    if (threadIdx.x == 255) bsum[blockIdx.x] = sh[255];
}

__global__ void scan2_k(int* __restrict__ bsum, int NB) {
    __shared__ int sh[256];
    int v = (threadIdx.x < NB) ? bsum[threadIdx.x] : 0;
    sh[threadIdx.x] = v;
    __syncthreads();
#pragma unroll
    for (int off = 1; off < 256; off <<= 1) {
        int t = (threadIdx.x >= off) ? sh[threadIdx.x - off] : 0;
        __syncthreads();
        sh[threadIdx.x] += t;
        __syncthreads();
    }
    if (threadIdx.x < NB) bsum[threadIdx.x] = sh[threadIdx.x] - v;  // exclusive
}

// rowptr/cursor + dinv fused
__global__ void scan3_k(const int* __restrict__ cnt, const int* __restrict__ incl,
                        const int* __restrict__ bsum, int* __restrict__ rowptr,
                        int* __restrict__ cursor, float* __restrict__ dinv,
                        int N, int E) {
    int i = blockIdx.x * 256 + threadIdx.x;
    if (i < N) {
        int c = cnt[i];
        int excl = incl[i] - c + bsum[blockIdx.x];
        rowptr[i] = excl;
        cursor[i] = excl;
        dinv[i] = rsqrtf(1.0f + (float)c);  // +1 self-loop
    }
    if (i == 0) rowptr[N] = E;
}

__global__ void fill_col_k(const int* __restrict__ src, const int* __restrict__ dst,
                           int* __restrict__ cursor, int* __restrict__ col, int E) {
    int e = blockIdx.x * blockDim.x + threadIdx.x;
    if (e < E) {
        int pos = atomicAdd(&cursor[dst[e]], 1);
        col[pos] = src[e];
    }
}

// ---------------------------------------------------------------------------
// Tiled fp32 GEMM: Out[M,BN] = (RELU? max(A,0):A)[M,128] @ W[128,BN], row-scaled
// by dscale. BM=64, BK=16, 256 threads. As stored k-major -> float4 LDS reads.
// Per k: 1x b128 (A) + TN/4 x b128 (B) + 4*TN FMA.
// ---------------------------------------------------------------------------
template <int BN, bool RELU>
__global__ __launch_bounds__(256) void gemm_k128(const float* __restrict__ A,
                                                 const float* __restrict__ W,
                                                 const float* __restrict__ dscale,
                                                 float* __restrict__ Out, int M) {
    constexpr int K = 128, BM = 64, BK = 16;
    constexpr int TN = BN / 16;
    __shared__ float As[BK][BM + 4];  // row stride 272B (16B-aligned); write conflicts 2-way (free)
    __shared__ float Bs[BK][BN];

    const int tid = threadIdx.x;
    const int tx = tid & 15, ty = tid >> 4;
    const int row0 = blockIdx.x * BM;

    float acc[4][TN];
#pragma unroll
    for (int m = 0; m < 4; m++)
#pragma unroll
        for (int j = 0; j < TN; j++) acc[m][j] = 0.0f;

    const int ar = tid >> 2;        // 0..63: A row within tile
    const int ak = (tid & 3) * 4;   // 0,4,8,12: k-offset of this thread's float4

    for (int kt = 0; kt < K; kt += BK) {
        // --- stage A tile (transposed to k-major) ---
        float4 av = make_float4(0.f, 0.f, 0.f, 0.f);
        int grow = row0 + ar;
        if (grow < M)
            av = *reinterpret_cast<const float4*>(A + (size_t)grow * K + kt + ak);
        if (RELU) {
            av.x = fmaxf(av.x, 0.f); av.y = fmaxf(av.y, 0.f);
            av.z = fmaxf(av.z, 0.f); av.w = fmaxf(av.w, 0.f);
        }
        As[ak + 0][ar] = av.x; As[ak + 1][ar] = av.y;
        As[ak + 2][ar] = av.z; As[ak + 3][ar] = av.w;

        // --- stage B tile (16xBN) ---
        constexpr int NB4 = BK * BN / 4;
#pragma unroll
        for (int b = 0; b < NB4 / 256; b++) {
            int f = b * 256 + tid;
            int brow = (f * 4) / BN;
            int bcol = (f * 4) % BN;
            float4 bv = *reinterpret_cast<const float4*>(W + (size_t)(kt + brow) * BN + bcol);
            *reinterpret_cast<float4*>(&Bs[brow][bcol]) = bv;
        }
        __syncthreads();

#pragma unroll
        for (int k = 0; k < BK; k++) {
            float4 a4 = *reinterpret_cast<const float4*>(&As[k][ty * 4]);
            float a[4] = {a4.x, a4.y, a4.z, a4.w};
            float bb[TN];
#pragma unroll
            for (int j4 = 0; j4 < TN / 4; j4++) {
                float4 b4 = *reinterpret_cast<const float4*>(&Bs[k][tx * TN + j4 * 4]);
                bb[j4 * 4 + 0] = b4.x; bb[j4 * 4 + 1] = b4.y;
                bb[j4 * 4 + 2] = b4.z; bb[j4 * 4 + 3] = b4.w;
            }
#pragma unroll
            for (int m = 0; m < 4; m++)
#pragma unroll
                for (int j = 0; j < TN; j++) acc[m][j] = fmaf(a[m], bb[j], acc[m][j]);
        }
        __syncthreads();
    }

#pragma unroll
    for (int m = 0; m < 4; m++) {
        int gr = row0 + ty * 4 + m;
        if (gr < M) {
            float dv = dscale[gr];
#pragma unroll
            for (int j4 = 0; j4 < TN / 4; j4++) {
                float4 o = make_float4(acc[m][j4 * 4 + 0] * dv, acc[m][j4 * 4 + 1] * dv,
                                       acc[m][j4 * 4 + 2] * dv, acc[m][j4 * 4 + 3] * dv);
                *reinterpret_cast<float4*>(Out + (size_t)gr * BN + tx * TN + j4 * 4) = o;
            }
        }
    }
}

// ---------------------------------------------------------------------------
// Pull aggregation, one wave per node, 4-edge unroll for gather ILP.
// out[v] = dinv[v] * ( hs[v] + sum_nbrs hs[col[p]] ) + bias
// ---------------------------------------------------------------------------
template <int D>
__global__ __launch_bounds__(256) void pull_k(const int* __restrict__ rowptr,
                                              const int* __restrict__ col,
                                              const float* __restrict__ hs,
                                              const float* __restrict__ dinv,
                                              const float* __restrict__ bias,
                                              float* __restrict__ out, int N) {
    int v = (int)((blockIdx.x * (size_t)blockDim.x + threadIdx.x) >> 6);
    int lane = threadIdx.x & 63;
    if (v >= N) return;
    int p0 = rowptr[v], p1 = rowptr[v + 1];
    float dv = dinv[v];

    if (D == 128) {
        const float2* base = reinterpret_cast<const float2*>(hs);  // row = 64 float2
        float2 s = base[(size_t)v * 64 + lane];
        float sx = s.x, sy = s.y;
        int p = p0;
        for (; p + 4 <= p1; p += 4) {
            int i0 = col[p], i1 = col[p + 1], i2 = col[p + 2], i3 = col[p + 3];
            float2 a = base[(size_t)i0 * 64 + lane];
            float2 b = base[(size_t)i1 * 64 + lane];
            float2 c = base[(size_t)i2 * 64 + lane];
            float2 d = base[(size_t)i3 * 64 + lane];
            sx += (a.x + b.x) + (c.x + d.x);
            sy += (a.y + b.y) + (c.y + d.y);
        }
        for (; p < p1; p++) {
            float2 a = base[(size_t)col[p] * 64 + lane];
            sx += a.x; sy += a.y;
        }
        float2 bv = reinterpret_cast<const float2*>(bias)[lane];
        float2 o = make_float2(fmaf(sx, dv, bv.x), fmaf(sy, dv, bv.y));
        reinterpret_cast<float2*>(out)[(size_t)v * 64 + lane] = o;
    } else {
        float acc = hs[(size_t)v * 64 + lane];
        int p = p0;
        for (; p + 4 <= p1; p += 4) {
            int i0 = col[p], i1 = col[p + 1], i2 = col[p + 2], i3 = col[p + 3];
            float a = hs[(size_t)i0 * 64 + lane];
            float b = hs[(size_t)i1 * 64 + lane];
            float c = hs[(size_t)i2 * 64 + lane];
            float d = hs[(size_t)i3 * 64 + lane];
            acc += (a + b) + (c + d);
        }
        for (; p < p1; p++) acc += hs[(size_t)col[p] * 64 + lane];
        out[(size_t)v * 64 + lane] = fmaf(acc, dv, bias[lane]);
    }
}

// logits: 2 edges per 16-lane group (4 float4 gathers in flight per lane)
__global__ void logits_k(const int* __restrict__ src, const int* __restrict__ dst,
                         const float* __restrict__ h2, float* __restrict__ out, int E) {
    int t = blockIdx.x * blockDim.x + threadIdx.x;
    int g = t >> 4, q = t & 15;
    int e0 = g * 2, e1 = e0 + 1;
    if (e0 >= E) return;
    int s0 = src[e0], d0 = dst[e0];
    float4 a0 = *reinterpret_cast<const float4*>(h2 + (size_t)s0 * 64 + q * 4);
    float4 b0 = *reinterpret_cast<const float4*>(h2 + (size_t)d0 * 64 + q * 4);
    bool has1 = (e1 < E);
    int s1 = has1 ? src[e1] : s0, d1 = has1 ? dst[e1] : d0;
    float4 a1 = *reinterpret_cast<const float4*>(h2 + (size_t)s1 * 64 + q * 4);
    float4 b1 = *reinterpret_cast<const float4*>(h2 + (size_t)d1 * 64 + q * 4);
    float p0 = a0.x * b0.x + a0.y * b0.y + a0.z * b0.z + a0.w * b0.w;
    float p1 = a1.x * b1.x + a1.y * b1.y + a1.z * b1.z + a1.w * b1.w;
#pragma unroll
    for (int off = 1; off < 16; off <<= 1) {
        p0 += __shfl_xor(p0, off);
        p1 += __shfl_xor(p1, off);
    }
    if (q == 0) {
        out[e0] = p0;
        if (has1) out[e1] = p1;
    }
}

extern "C" void kernel_launch(void* const* d_in, const int* in_sizes, int n_in,
                              void* d_out, int out_size, void* d_ws, size_t ws_size,
                              hipStream_t stream) {
    const float* x  = (const float*)d_in[0];
    const int* ei   = (const int*)d_in[1];   // int32 (harness converts ints)
    const float* W1 = (const float*)d_in[2];
    const float* b1 = (const float*)d_in[3];
    const float* W2 = (const float*)d_in[4];
    const float* b2 = (const float*)d_in[5];
    float* out = (float*)d_out;

    const int N = in_sizes[0] / 128;   // 50000
    const int E = in_sizes[1] / 2;     // 800000
    const int* src = ei;
    const int* dst = ei + E;

    // ---- workspace layout ----
    float* ws   = (float*)d_ws;
    float* dinv = ws;
    float* bufA = ws + 50176;
    float* bufB = bufA + (size_t)N * 128;
    float* hs1  = bufA;
    float* agg1 = bufB;
    float* g2s  = bufA;
    float* agg2 = bufA + (size_t)N * 64;

    int* ibase  = (int*)(bufB + (size_t)N * 128);
    int* cnt    = ibase;
    int* incl   = cnt + N;
    int* rowptr = incl + N;
    int* cursor = rowptr + (N + 1);
    int* bsum   = cursor + N;
    int* col    = bsum + 256;

    const int B = 256;
    const int NB = (N + 255) / 256;

    // ---- CSR build + dinv ----
    hipMemsetAsync(cnt, 0, (size_t)N * sizeof(int), stream);
    cnt_k<<<(E + B - 1) / B, B, 0, stream>>>(dst, cnt, E);
    scan1_k<<<NB, 256, 0, stream>>>(cnt, incl, bsum, N);
    scan2_k<<<1, 256, 0, stream>>>(bsum, NB);
    scan3_k<<<NB, 256, 0, stream>>>(cnt, incl, bsum, rowptr, cursor, dinv, N, E);
    fill_col_k<<<(E + B - 1) / B, B, 0, stream>>>(src, dst, cursor, col, E);

    // ---- layer 1 ----
    gemm_k128<128, false><<<(N + 63) / 64, 256, 0, stream>>>(x, W1, dinv, hs1, N);
    pull_k<128><<<((size_t)N * 64 + 255) / 256, 256, 0, stream>>>(rowptr, col, hs1, dinv, b1, agg1, N);

    // ---- layer 2 ----
    gemm_k128<64, true><<<(N + 63) / 64, 256, 0, stream>>>(agg1, W2, dinv, g2s, N);
    pull_k<64><<<((size_t)N * 64 + 255) / 256, 256, 0, stream>>>(rowptr, col, g2s, dinv, b2, agg2, N);

    // ---- edge logits ----
    {
        size_t groups = ((size_t)E + 1) / 2;
        logits_k<<<(groups * 16 + 255) / 256, 256, 0, stream>>>(src, dst, agg2, out, E);
    }
}

// Round 5
// 276.197 us; speedup vs baseline: 7.9405x; 1.0331x over previous
//
#include <hip/hip_runtime.h>
#include <hip/hip_bf16.h>

// ---------------------------------------------------------------------------
// GCN 2-layer + edge dot logits, CSR-pull aggregation.
// agg[d] = dinv[d] * ( sum_{s in in(d)} hs[s] + hs[d] ) + b,  hs = (A@W)*dinv[row]
// Pulls use multi-row-per-wave float4 gathers; logits reuse CSR (dst row loaded
// once, only src side gathered).
// ---------------------------------------------------------------------------

__global__ void cnt_k(const int* __restrict__ dst, int* __restrict__ cnt, int E) {
    int e = blockIdx.x * blockDim.x + threadIdx.x;
    if (e < E) atomicAdd(&cnt[dst[e]], 1);
}

__global__ void scan1_k(const int* __restrict__ cnt, int* __restrict__ incl,
                        int* __restrict__ bsum, int N) {
    __shared__ int sh[256];
    int i = blockIdx.x * 256 + threadIdx.x;
    int v = (i < N) ? cnt[i] : 0;
    sh[threadIdx.x] = v;
    __syncthreads();
#pragma unroll
    for (int off = 1; off < 256; off <<= 1) {
        int t = (threadIdx.x >= off) ? sh[threadIdx.x - off] : 0;
        __syncthreads();
        sh[threadIdx.x] += t;
        __syncthreads();
    }
    if (i < N) incl[i] = sh[threadIdx.x];
    if (threadIdx.x == 255) bsum[blockIdx.x] = sh[255];
}

__global__ void scan2_k(int* __restrict__ bsum, int NB) {
    __shared__ int sh[256];
    int v = (threadIdx.x < NB) ? bsum[threadIdx.x] : 0;
    sh[threadIdx.x] = v;
    __syncthreads();
#pragma unroll
    for (int off = 1; off < 256; off <<= 1) {
        int t = (threadIdx.x >= off) ? sh[threadIdx.x - off] : 0;
        __syncthreads();
        sh[threadIdx.x] += t;
        __syncthreads();
    }
    if (threadIdx.x < NB) bsum[threadIdx.x] = sh[threadIdx.x] - v;  // exclusive
}

__global__ void scan3_k(const int* __restrict__ cnt, const int* __restrict__ incl,
                        const int* __restrict__ bsum, int* __restrict__ rowptr,
                        int* __restrict__ cursor, float* __restrict__ dinv,
                        int N, int E) {
    int i = blockIdx.x * 256 + threadIdx.x;
    if (i < N) {
        int c = cnt[i];
        int excl = incl[i] - c + bsum[blockIdx.x];
        rowptr[i] = excl;
        cursor[i] = excl;
        dinv[i] = rsqrtf(1.0f + (float)c);
    }
    if (i == 0) rowptr[N] = E;
}

__global__ void fill_col_k(const int* __restrict__ src, const int* __restrict__ dst,
                           int* __restrict__ cursor, int* __restrict__ col,
                           int* __restrict__ eid, int E) {
    int e = blockIdx.x * blockDim.x + threadIdx.x;
    if (e < E) {
        int pos = atomicAdd(&cursor[dst[e]], 1);
        col[pos] = src[e];
        eid[pos] = e;
    }
}

// ---------------------------------------------------------------------------
// Tiled fp32 GEMM (k-major As): Out = (RELU? relu(A):A)[M,128] @ W[128,BN] * dscale[row]
// ---------------------------------------------------------------------------
template <int BN, bool RELU>
__global__ __launch_bounds__(256) void gemm_k128(const float* __restrict__ A,
                                                 const float* __restrict__ W,
                                                 const float* __restrict__ dscale,
                                                 float* __restrict__ Out, int M) {
    constexpr int K = 128, BM = 64, BK = 16;
    constexpr int TN = BN / 16;
    __shared__ float As[BK][BM + 4];
    __shared__ float Bs[BK][BN];

    const int tid = threadIdx.x;
    const int tx = tid & 15, ty = tid >> 4;
    const int row0 = blockIdx.x * BM;

    float acc[4][TN];
#pragma unroll
    for (int m = 0; m < 4; m++)
#pragma unroll
        for (int j = 0; j < TN; j++) acc[m][j] = 0.0f;

    const int ar = tid >> 2;
    const int ak = (tid & 3) * 4;

    for (int kt = 0; kt < K; kt += BK) {
        float4 av = make_float4(0.f, 0.f, 0.f, 0.f);
        int grow = row0 + ar;
        if (grow < M)
            av = *reinterpret_cast<const float4*>(A + (size_t)grow * K + kt + ak);
        if (RELU) {
            av.x = fmaxf(av.x, 0.f); av.y = fmaxf(av.y, 0.f);
            av.z = fmaxf(av.z, 0.f); av.w = fmaxf(av.w, 0.f);
        }
        As[ak + 0][ar] = av.x; As[ak + 1][ar] = av.y;
        As[ak + 2][ar] = av.z; As[ak + 3][ar] = av.w;

        constexpr int NB4 = BK * BN / 4;
#pragma unroll
        for (int b = 0; b < NB4 / 256; b++) {
            int f = b * 256 + tid;
            int brow = (f * 4) / BN;
            int bcol = (f * 4) % BN;
            float4 bv = *reinterpret_cast<const float4*>(W + (size_t)(kt + brow) * BN + bcol);
            *reinterpret_cast<float4*>(&Bs[brow][bcol]) = bv;
        }
        __syncthreads();

#pragma unroll
        for (int k = 0; k < BK; k++) {
            float4 a4 = *reinterpret_cast<const float4*>(&As[k][ty * 4]);
            float a[4] = {a4.x, a4.y, a4.z, a4.w};
            float bb[TN];
#pragma unroll
            for (int j4 = 0; j4 < TN / 4; j4++) {
                float4 b4 = *reinterpret_cast<const float4*>(&Bs[k][tx * TN + j4 * 4]);
                bb[j4 * 4 + 0] = b4.x; bb[j4 * 4 + 1] = b4.y;
                bb[j4 * 4 + 2] = b4.z; bb[j4 * 4 + 3] = b4.w;
            }
#pragma unroll
            for (int m = 0; m < 4; m++)
#pragma unroll
                for (int j = 0; j < TN; j++) acc[m][j] = fmaf(a[m], bb[j], acc[m][j]);
        }
        __syncthreads();
    }

#pragma unroll
    for (int m = 0; m < 4; m++) {
        int gr = row0 + ty * 4 + m;
        if (gr < M) {
            float dv = dscale[gr];
#pragma unroll
            for (int j4 = 0; j4 < TN / 4; j4++) {
                float4 o = make_float4(acc[m][j4 * 4 + 0] * dv, acc[m][j4 * 4 + 1] * dv,
                                       acc[m][j4 * 4 + 2] * dv, acc[m][j4 * 4 + 3] * dv);
                *reinterpret_cast<float4*>(Out + (size_t)gr * BN + tx * TN + j4 * 4) = o;
            }
        }
    }
}

// ---------------------------------------------------------------------------
// pull128: one wave per node. lanes 0-31 = neighbor slot 0, lanes 32-63 = slot 1.
// Each slot gathers a full 512B row as 32 lanes x float4. 4-pair unroll.
// ---------------------------------------------------------------------------
__global__ __launch_bounds__(256) void pull128_k(const int* __restrict__ rowptr,
                                                 const int* __restrict__ col,
                                                 const float4* __restrict__ hs4,
                                                 const float* __restrict__ dinv,
                                                 const float4* __restrict__ bias4,
                                                 float4* __restrict__ out4, int N) {
    int v = (int)((blockIdx.x * (size_t)blockDim.x + threadIdx.x) >> 6);
    if (v >= N) return;
    int lane = threadIdx.x & 63;
    int q = lane & 31, slot = lane >> 5;
    int p0 = rowptr[v], p1 = rowptr[v + 1];

    float4 acc = make_float4(0.f, 0.f, 0.f, 0.f);
    if (slot == 0) acc = hs4[(size_t)v * 32 + q];  // self row

    int p = p0;
    for (; p + 8 <= p1; p += 8) {
        int ia = col[p + slot], ib = col[p + 2 + slot];
        int ic = col[p + 4 + slot], id = col[p + 6 + slot];
        float4 a = hs4[(size_t)ia * 32 + q];
        float4 b = hs4[(size_t)ib * 32 + q];
        float4 c = hs4[(size_t)ic * 32 + q];
        float4 d = hs4[(size_t)id * 32 + q];
        acc.x += (a.x + b.x) + (c.x + d.x);
        acc.y += (a.y + b.y) + (c.y + d.y);
        acc.z += (a.z + b.z) + (c.z + d.z);
        acc.w += (a.w + b.w) + (c.w + d.w);
    }
    for (; p + 2 <= p1; p += 2) {
        int ia = col[p + slot];
        float4 a = hs4[(size_t)ia * 32 + q];
        acc.x += a.x; acc.y += a.y; acc.z += a.z; acc.w += a.w;
    }
    if (p < p1 && slot == 0) {
        float4 a = hs4[(size_t)col[p] * 32 + q];
        acc.x += a.x; acc.y += a.y; acc.z += a.z; acc.w += a.w;
    }

    acc.x += __shfl_xor(acc.x, 32);
    acc.y += __shfl_xor(acc.y, 32);
    acc.z += __shfl_xor(acc.z, 32);
    acc.w += __shfl_xor(acc.w, 32);

    if (slot == 0) {
        float dv = dinv[v];
        float4 bv = bias4[q];
        out4[(size_t)v * 32 + q] = make_float4(fmaf(acc.x, dv, bv.x), fmaf(acc.y, dv, bv.y),
                                               fmaf(acc.z, dv, bv.z), fmaf(acc.w, dv, bv.w));
    }
}

// ---------------------------------------------------------------------------
// pull64: one wave per node, 4 slots of 16 lanes; each slot = one 256B row. 2x unroll.
// ---------------------------------------------------------------------------
__global__ __launch_bounds__(256) void pull64_k(const int* __restrict__ rowptr,
                                                const int* __restrict__ col,
                                                const float4* __restrict__ hs4,
                                                const float* __restrict__ dinv,
                                                const float4* __restrict__ bias4,
                                                float4* __restrict__ out4, int N) {
    int v = (int)((blockIdx.x * (size_t)blockDim.x + threadIdx.x) >> 6);
    if (v >= N) return;
    int lane = threadIdx.x & 63;
    int q = lane & 15, slot = lane >> 4;
    int p0 = rowptr[v], p1 = rowptr[v + 1];

    float4 acc = make_float4(0.f, 0.f, 0.f, 0.f);
    if (slot == 0) acc = hs4[(size_t)v * 16 + q];  // self row

    int p = p0;
    for (; p + 8 <= p1; p += 8) {
        int ia = col[p + slot], ib = col[p + 4 + slot];
        float4 a = hs4[(size_t)ia * 16 + q];
        float4 b = hs4[(size_t)ib * 16 + q];
        acc.x += a.x + b.x; acc.y += a.y + b.y;
        acc.z += a.z + b.z; acc.w += a.w + b.w;
    }
    for (; p + 4 <= p1; p += 4) {
        float4 a = hs4[(size_t)col[p + slot] * 16 + q];
        acc.x += a.x; acc.y += a.y; acc.z += a.z; acc.w += a.w;
    }
    int rem = p1 - p;  // 0..3
    if (slot < rem) {
        float4 a = hs4[(size_t)col[p + slot] * 16 + q];
        acc.x += a.x; acc.y += a.y; acc.z += a.z; acc.w += a.w;
    }

#pragma unroll
    for (int off = 16; off <= 32; off <<= 1) {
        acc.x += __shfl_xor(acc.x, off);
        acc.y += __shfl_xor(acc.y, off);
        acc.z += __shfl_xor(acc.z, off);
        acc.w += __shfl_xor(acc.w, off);
    }

    if (slot == 0) {
        float dv = dinv[v];
        float4 bv = bias4[q];
        out4[(size_t)v * 16 + q] = make_float4(fmaf(acc.x, dv, bv.x), fmaf(acc.y, dv, bv.y),
                                               fmaf(acc.z, dv, bv.z), fmaf(acc.w, dv, bv.w));
    }
}

// ---------------------------------------------------------------------------
// logits via CSR: one wave per dst node; dst row loaded once (broadcast), only
// src rows gathered. 4 slots x 16 lanes, slot = one edge; 2x unroll.
// ---------------------------------------------------------------------------
__global__ __launch_bounds__(256) void logits_csr_k(const int* __restrict__ rowptr,
                                                    const int* __restrict__ col,
                                                    const int* __restrict__ eid,
                                                    const float4* __restrict__ h4,
                                                    float* __restrict__ out, int N) {
    int v = (int)((blockIdx.x * (size_t)blockDim.x + threadIdx.x) >> 6);
    if (v >= N) return;
    int lane = threadIdx.x & 63;
    int q = lane & 15, slot = lane >> 4;
    int p0 = rowptr[v], p1 = rowptr[v + 1];
    if (p0 == p1) return;

    float4 rd = h4[(size_t)v * 16 + q];  // dst row, loaded once per wave

    int p = p0;
    for (; p + 8 <= p1; p += 8) {
        int s0 = col[p + slot], s1 = col[p + 4 + slot];
        int e0 = eid[p + slot], e1 = eid[p + 4 + slot];
        float4 ra = h4[(size_t)s0 * 16 + q];
        float4 rb = h4[(size_t)s1 * 16 + q];
        float t0 = rd.x * ra.x + rd.y * ra.y + rd.z * ra.z + rd.w * ra.w;
        float t1 = rd.x * rb.x + rd.y * rb.y + rd.z * rb.z + rd.w * rb.w;
#pragma unroll
        for (int off = 1; off < 16; off <<= 1) {
            t0 += __shfl_xor(t0, off);
            t1 += __shfl_xor(t1, off);
        }
        if (q == 0) { out[e0] = t0; out[e1] = t1; }
    }
    for (; p + 4 <= p1; p += 4) {
        int s0 = col[p + slot];
        int e0 = eid[p + slot];
        float4 ra = h4[(size_t)s0 * 16 + q];
        float t0 = rd.x * ra.x + rd.y * ra.y + rd.z * ra.z + rd.w * ra.w;
#pragma unroll
        for (int off = 1; off < 16; off <<= 1) t0 += __shfl_xor(t0, off);
        if (q == 0) out[e0] = t0;
    }
    int rem = p1 - p;  // 0..3; whole 16-lane slot groups are uniformly active
    if (slot < rem) {
        int s0 = col[p + slot];
        int e0 = eid[p + slot];
        float4 ra = h4[(size_t)s0 * 16 + q];
        float t0 = rd.x * ra.x + rd.y * ra.y + rd.z * ra.z + rd.w * ra.w;
#pragma unroll
        for (int off = 1; off < 16; off <<= 1) t0 += __shfl_xor(t0, off);
        if (q == 0) out[e0] = t0;
    }
}

extern "C" void kernel_launch(void* const* d_in, const int* in_sizes, int n_in,
                              void* d_out, int out_size, void* d_ws, size_t ws_size,
                              hipStream_t stream) {
    const float* x  = (const float*)d_in[0];
    const int* ei   = (const int*)d_in[1];   // int32 (harness converts ints)
    const float* W1 = (const float*)d_in[2];
    const float* b1 = (const float*)d_in[3];
    const float* W2 = (const float*)d_in[4];
    const float* b2 = (const float*)d_in[5];
    float* out = (float*)d_out;

    const int N = in_sizes[0] / 128;   // 50000
    const int E = in_sizes[1] / 2;     // 800000
    const int* src = ei;
    const int* dst = ei + E;

    // ---- workspace ----
    // floats: dinv[50176] | bufA[N*128] | bufB[N*128]
    // ints:   cnt[N] | incl[N] | rowptr[N+1] | cursor[N] | bsum[256] | col[E] | eid[E]
    float* ws   = (float*)d_ws;
    float* dinv = ws;
    float* bufA = ws + 50176;
    float* bufB = bufA + (size_t)N * 128;
    float* hs1  = bufA;
    float* agg1 = bufB;
    float* g2s  = bufA;
    float* agg2 = bufA + (size_t)N * 64;

    int* ibase  = (int*)(bufB + (size_t)N * 128);
    int* cnt    = ibase;
    int* incl   = cnt + N;
    int* rowptr = incl + N;
    int* cursor = rowptr + (N + 1);
    int* bsum   = cursor + N;
    int* col    = bsum + 256;
    int* eid    = col + E;

    const int B = 256;
    const int NB = (N + 255) / 256;
    const unsigned nodeBlocks = (unsigned)(((size_t)N * 64 + 255) / 256);

    // ---- CSR build + dinv ----
    hipMemsetAsync(cnt, 0, (size_t)N * sizeof(int), stream);
    cnt_k<<<(E + B - 1) / B, B, 0, stream>>>(dst, cnt, E);
    scan1_k<<<NB, 256, 0, stream>>>(cnt, incl, bsum, N);
    scan2_k<<<1, 256, 0, stream>>>(bsum, NB);
    scan3_k<<<NB, 256, 0, stream>>>(cnt, incl, bsum, rowptr, cursor, dinv, N, E);
    fill_col_k<<<(E + B - 1) / B, B, 0, stream>>>(src, dst, cursor, col, eid, E);

    // ---- layer 1 ----
    gemm_k128<128, false><<<(N + 63) / 64, 256, 0, stream>>>(x, W1, dinv, hs1, N);
    pull128_k<<<nodeBlocks, 256, 0, stream>>>(rowptr, col, (const float4*)hs1, dinv,
                                              (const float4*)b1, (float4*)agg1, N);

    // ---- layer 2 ----
    gemm_k128<64, true><<<(N + 63) / 64, 256, 0, stream>>>(agg1, W2, dinv, g2s, N);
    pull64_k<<<nodeBlocks, 256, 0, stream>>>(rowptr, col, (const float4*)g2s, dinv,
                                             (const float4*)b2, (float4*)agg2, N);

    // ---- edge logits (CSR order, dst row amortized) ----
    logits_csr_k<<<nodeBlocks, 256, 0, stream>>>(rowptr, col, eid, (const float4*)agg2, out, N);
}